// Round 3
// 1005.113 us; speedup vs baseline: 1.3976x; 1.3976x over previous
//
#include <hip/hip_runtime.h>
#include <float.h>

// ---------------------------------------------------------------------------
// OnlineClustering: normalize -> GEMM (bf16 MFMA, colmax fused in epilogue) ->
// Sinkhorn (factorized, fused row+col pass per iteration) -> assignments+loss.
//
// Factorization: M_final[s,k] = M0[s,k] * C[b,k] * R[b,s],
//   M0 = exp((l - shift_k)/T + 50).
// Iteration i (fused kernel): w_s = sum_k M0*C_i ; R_i = R/(R*w+eps) ;
//   t_{i+1,k} += sum_s M0*R_i   (accumulated in-register, atomics at end).
// Last iteration also emits assignments + CE loss directly from registers.
// (Round-2 fix: nontemporal stores go through ext_vector_type v4f, not HIP
//  float4 — the builtin rejects struct vector types.)
// ---------------------------------------------------------------------------

#define TT_INV 14.285714285714286f   // 1/0.07
#define TP_INV 8.333333333333334f    // 1/0.12
#define EXPMAX 50.0f
#define SK_EPS 1e-8f

typedef short v8s __attribute__((ext_vector_type(8)));
typedef float v4f __attribute__((ext_vector_type(4)));

__device__ inline unsigned short f2bf(float f){          // RNE float->bf16
  unsigned u = __float_as_uint(f);
  u += 0x7FFFu + ((u >> 16) & 1u);
  return (unsigned short)(u >> 16);
}
// order-preserving float<->uint for atomicMax on floats (incl. negatives)
__device__ inline unsigned encf(float f){
  unsigned u = __float_as_uint(f);
  return (u & 0x80000000u) ? ~u : (u | 0x80000000u);
}
__device__ inline float decf(unsigned e){
  unsigned u = (e & 0x80000000u) ? (e & 0x7FFFFFFFu) : ~e;
  return __uint_as_float(u);
}

__device__ inline float wredsum(float v){
  #pragma unroll
  for(int o = 32; o; o >>= 1) v += __shfl_down(v, o);
  return v;
}
__device__ inline float wredmax(float v){
  #pragma unroll
  for(int o = 32; o; o >>= 1) v = fmaxf(v, __shfl_down(v, o));
  return v;
}
__device__ inline float4 m0exp(const float4 v, const float4 sh){
  float4 r;
  r.x = __expf((v.x - sh.x)*TT_INV + EXPMAX);
  r.y = __expf((v.y - sh.y)*TT_INV + EXPMAX);
  r.z = __expf((v.z - sh.z)*TT_INV + EXPMAX);
  r.w = __expf((v.w - sh.w)*TT_INV + EXPMAX);
  return r;
}

// block = 256 threads (4 waves)
__device__ inline float blockReduceSum(float v, float* sb){
  v = wredsum(v);
  __syncthreads();
  if((threadIdx.x & 63) == 0) sb[threadIdx.x >> 6] = v;
  __syncthreads();
  return (sb[0] + sb[1]) + (sb[2] + sb[3]);
}

__device__ inline void gl_lds16(const void* g, void* l){
  __builtin_amdgcn_global_load_lds(
      (const __attribute__((address_space(1))) void*)g,
      (__attribute__((address_space(3))) void*)l, 16, 0, 0);
}

// -------------------- init small buffers --------------------
__global__ __launch_bounds__(256) void init_k(unsigned* __restrict__ shiftenc,
                                              float* __restrict__ tbuf,
                                              float* __restrict__ Cb,
                                              float* __restrict__ Rb,
                                              float* __restrict__ lossacc){
  int i = blockIdx.x * 256 + threadIdx.x;   // grid covers 262144
  shiftenc[i] = 0u;       // encf(any real) > 0, so 0 is below any real value
  tbuf[i] = 0.f;
  Cb[i] = 1.f;
  if(i < 8192) Rb[i] = 1.f;
  if(i == 0) lossacc[0] = 0.f;
}

// -------------------- normalize x rows, cast bf16 --------------------
__global__ __launch_bounds__(256) void norm_x_k(const float* __restrict__ x,
                                                unsigned short* __restrict__ xb){
  const int row = blockIdx.x, t = threadIdx.x;
  const float4 v = ((const float4*)(x + (size_t)row * 1024))[t];
  __shared__ float sb[4];
  float ss = v.x*v.x + v.y*v.y + v.z*v.z + v.w*v.w;
  float tot = blockReduceSum(ss, sb);
  float sc = 1.0f / fmaxf(sqrtf(tot), 1e-7f);
  ushort4 o = { f2bf(v.x*sc), f2bf(v.y*sc), f2bf(v.z*sc), f2bf(v.w*sc) };
  ((ushort4*)(xb + (size_t)row * 1024))[t] = o;
}

// -------------------- cast W bf16 --------------------
__global__ __launch_bounds__(256) void conv_w_k(const float* __restrict__ W,
                                                unsigned short* __restrict__ Wb){
  const size_t i = (size_t)blockIdx.x * 256 + threadIdx.x;
  const float4 v = ((const float4*)W)[i];
  ushort4 o = { f2bf(v.x), f2bf(v.y), f2bf(v.z), f2bf(v.w) };
  ((ushort4*)Wb)[i] = o;
}

// -------------------- bf16 GEMM (B^T form): C[m][n] = sum_d A[m][d]*B[n][d] --
// 128x128 block tile, BK=32, 4 waves each 64x64, global_load_lds width-16.
// XCD-aware swizzle: each XCD works an 8x8 tile neighborhood (A/B panels fit
// its private L2). Epilogue also computes per-(batch,col) max via atomicMax.
__global__ __launch_bounds__(256) void gemm_bt_k(const unsigned short* __restrict__ A,
                                                 const unsigned short* __restrict__ B,
                                                 float* __restrict__ C,
                                                 unsigned* __restrict__ shiftenc){
  __shared__ __align__(16) short As[128 * 32];
  __shared__ __align__(16) short Bs[128 * 32];
  const int t = threadIdx.x;
  const int L = t & 63, w = t >> 6;
  const int wm = w >> 1, wn = w & 1;
  const int quad = L >> 4, lr = L & 15;

  // bid -> (by,bx): bijective; XCD x (= bid%8, dispatch round-robin heuristic)
  // owns by in [x*8,x*8+8); within the chunk, 8x8 tile groups run together.
  const int bid = blockIdx.x;
  const int xcd = bid & 7;
  const int c   = bid >> 3;               // 0..511
  const int by  = xcd * 8 + ((c >> 3) & 7);
  const int bx  = (c >> 6) * 8 + (c & 7);
  const int m0 = by * 128, n0 = bx * 128;

  v4f acc[4][4];
  #pragma unroll
  for(int i = 0; i < 4; i++)
    #pragma unroll
    for(int j = 0; j < 4; j++) acc[i][j] = (v4f){0.f, 0.f, 0.f, 0.f};

  // staging chunks: 512 16B-chunks per tile, 2 per thread per tile
  const int c0 = t, c1 = t + 256;
  const int r0 = c0 >> 2, kc0 = c0 & 3;
  const int r1 = c1 >> 2, kc1 = c1 & 3;
  const unsigned short* gA0 = A + (size_t)(m0 + r0) * 1024 + kc0 * 8;
  const unsigned short* gA1 = A + (size_t)(m0 + r1) * 1024 + kc1 * 8;
  const unsigned short* gB0 = B + (size_t)(n0 + r0) * 1024 + kc0 * 8;
  const unsigned short* gB1 = B + (size_t)(n0 + r1) * 1024 + kc1 * 8;
  short* lA0 = &As[c0 * 8]; short* lA1 = &As[c1 * 8];
  short* lB0 = &Bs[c0 * 8]; short* lB1 = &Bs[c1 * 8];

  for(int kt = 0; kt < 32; ++kt){
    __syncthreads();
    const int ko = kt * 32;
    gl_lds16(gA0 + ko, lA0);
    gl_lds16(gA1 + ko, lA1);
    gl_lds16(gB0 + ko, lB0);
    gl_lds16(gB1 + ko, lB1);
    __syncthreads();
    v8s af[4], bf[4];
    #pragma unroll
    for(int mi = 0; mi < 4; mi++)
      af[mi] = *(const v8s*)&As[(wm*64 + mi*16 + lr) * 32 + quad * 8];
    #pragma unroll
    for(int ni = 0; ni < 4; ni++)
      bf[ni] = *(const v8s*)&Bs[(wn*64 + ni*16 + lr) * 32 + quad * 8];
    #pragma unroll
    for(int mi = 0; mi < 4; mi++)
      #pragma unroll
      for(int ni = 0; ni < 4; ni++)
        acc[mi][ni] = __builtin_amdgcn_mfma_f32_16x16x32_bf16(af[mi], bf[ni], acc[mi][ni], 0, 0, 0);
  }
  // C/D layout: col = lane&15, row = quad*4 + reg
  #pragma unroll
  for(int mi = 0; mi < 4; mi++){
    const int row = m0 + wm*64 + mi*16 + quad*4;
    #pragma unroll
    for(int ni = 0; ni < 4; ni++){
      const int col = n0 + wn*64 + ni*16 + lr;
      #pragma unroll
      for(int r = 0; r < 4; r++)
        C[(size_t)(row + r) * 8192 + col] = acc[mi][ni][r];
    }
  }
  // fused colmax: per column (this wave covers 64 rows of the wm-half)
  const int b = m0 >> 8;
  #pragma unroll
  for(int ni = 0; ni < 4; ni++){
    float m = acc[0][ni][0];
    #pragma unroll
    for(int mi = 0; mi < 4; mi++)
      #pragma unroll
      for(int r = 0; r < 4; r++) m = fmaxf(m, acc[mi][ni][r]);
    m = fmaxf(m, __shfl_xor(m, 16));
    m = fmaxf(m, __shfl_xor(m, 32));
    if(quad == 0){
      const int col = n0 + wn*64 + ni*16 + lr;
      atomicMax(shiftenc + (size_t)b * 8192 + col, encf(m));
    }
  }
}

// -------------------- t1 = sum_s M0 (R0 = 1), row-structured ----------------
// block = (sg row-group of 8 rows, batch b); t partials in registers,
// one atomicAdd per k-slot at the end.
__global__ __launch_bounds__(256) void colsum0_k(const float* __restrict__ logits,
                                                 const unsigned* __restrict__ shiftenc,
                                                 float* __restrict__ tbuf){
  const int sg = blockIdx.x, b = blockIdx.y, t = threadIdx.x;
  const unsigned* sep = shiftenc + (size_t)b * 8192;
  float4 sh[8];
  #pragma unroll
  for(int it = 0; it < 8; it++){
    uint4 u = *(const uint4*)(sep + it*1024 + t*4);
    sh[it] = (float4){ decf(u.x), decf(u.y), decf(u.z), decf(u.w) };
  }
  float4 tacc[8];
  #pragma unroll
  for(int it = 0; it < 8; it++) tacc[it] = (float4){0.f,0.f,0.f,0.f};

  const float* base = logits + (size_t)(b*256 + sg*8) * 8192;
  for(int rr = 0; rr < 8; rr++){
    const float* rp = base + (size_t)rr * 8192;
    #pragma unroll
    for(int it = 0; it < 8; it++){
      float4 v = *(const float4*)(rp + it*1024 + t*4);
      float4 e = m0exp(v, sh[it]);
      tacc[it].x += e.x; tacc[it].y += e.y; tacc[it].z += e.z; tacc[it].w += e.w;
    }
  }
  float* tp = tbuf + (size_t)b * 8192;
  #pragma unroll
  for(int it = 0; it < 8; it++){
    float* p = tp + it*1024 + t*4;
    atomicAdd(p + 0, tacc[it].x); atomicAdd(p + 1, tacc[it].y);
    atomicAdd(p + 2, tacc[it].z); atomicAdd(p + 3, tacc[it].w);
  }
}

// -------------------- C update (and reset t for next iter) --------------------
__global__ __launch_bounds__(256) void updC_k(float* __restrict__ Cb,
                                              float* __restrict__ tbuf){
  const int i = blockIdx.x * 256 + threadIdx.x;
  const float c = Cb[i], tt = tbuf[i];
  Cb[i] = c / (c * tt + SK_EPS);
  tbuf[i] = 0.f;
}

// -------------------- fused sinkhorn iteration ------------------------------
// Per block: 8 rows of one batch, 4 substeps of 2 rows held in registers.
//   w_s = sum_k M0*C ; R <- R/(R*w+eps) ; !LAST: tacc += M0*R (atomics at end)
//   LAST: assignments = M0*C*R -> out, CE-loss terms -> lossacc.
template<int LAST>
__global__ __launch_bounds__(256, 2) void iter_k(const float* __restrict__ logits,
                                                 const unsigned* __restrict__ shiftenc,
                                                 const float* __restrict__ Cb,
                                                 float* __restrict__ Rb,
                                                 float* __restrict__ tbuf,
                                                 float* __restrict__ out,
                                                 float* __restrict__ lossacc){
  const int sg = blockIdx.x, b = blockIdx.y, t = threadIdx.x;
  __shared__ float sb[24];
  const unsigned* sep = shiftenc + (size_t)b * 8192;
  const float* Cp = Cb + (size_t)b * 8192;

  float4 sh[8], c4[8];
  #pragma unroll
  for(int it = 0; it < 8; it++){
    uint4 u = *(const uint4*)(sep + it*1024 + t*4);
    sh[it] = (float4){ decf(u.x), decf(u.y), decf(u.z), decf(u.w) };
    c4[it] = *(const float4*)(Cp + it*1024 + t*4);
  }
  float4 tacc[8];
  if(!LAST){
    #pragma unroll
    for(int it = 0; it < 8; it++) tacc[it] = (float4){0.f,0.f,0.f,0.f};
  }

  const int wv = t >> 6;
  for(int sub = 0; sub < 4; sub++){
    const size_t gA = (size_t)(b*256 + sg*8 + sub*2);   // global row A (B = A+1)
    const float* pA = logits + gA * 8192;
    const float* pB = pA + 8192;
    // read old R BEFORE any barrier (t0 writes it after the barrier)
    const float RoA = Rb[gA], RoB = Rb[gA + 1];

    float4 va[8], vb[8];
    #pragma unroll
    for(int it = 0; it < 8; it++){
      va[it] = *(const float4*)(pA + it*1024 + t*4);
      vb[it] = *(const float4*)(pB + it*1024 + t*4);
    }
    float wA = 0.f, wB = 0.f, mA = -FLT_MAX, mB = -FLT_MAX;
    #pragma unroll
    for(int it = 0; it < 8; it++){
      float4 eA = m0exp(va[it], sh[it]);
      float4 eB = m0exp(vb[it], sh[it]);
      wA += (eA.x*c4[it].x + eA.y*c4[it].y) + (eA.z*c4[it].z + eA.w*c4[it].w);
      wB += (eB.x*c4[it].x + eB.y*c4[it].y) + (eB.z*c4[it].z + eB.w*c4[it].w);
      if(LAST){
        mA = fmaxf(mA, fmaxf(fmaxf(va[it].x, va[it].y), fmaxf(va[it].z, va[it].w)));
        mB = fmaxf(mB, fmaxf(fmaxf(vb[it].x, vb[it].y), fmaxf(vb[it].z, vb[it].w)));
      }
    }
    // round-1 block reduce: wA,wB (+Lmax for LAST)
    wA = wredsum(wA); wB = wredsum(wB);
    if(LAST){ mA = wredmax(mA); mB = wredmax(mB); }
    __syncthreads();
    if((t & 63) == 0){
      sb[wv] = wA; sb[4 + wv] = wB;
      if(LAST){ sb[8 + wv] = mA; sb[12 + wv] = mB; }
    }
    __syncthreads();
    wA = (sb[0] + sb[1]) + (sb[2] + sb[3]);
    wB = (sb[4] + sb[5]) + (sb[6] + sb[7]);
    if(LAST){
      mA = fmaxf(fmaxf(sb[8],  sb[9]),  fmaxf(sb[10], sb[11]));
      mB = fmaxf(fmaxf(sb[12], sb[13]), fmaxf(sb[14], sb[15]));
    }
    const float RnA = RoA / (RoA * wA + SK_EPS);
    const float RnB = RoB / (RoB * wB + SK_EPS);

    if(!LAST){
      if(t == 0){ Rb[gA] = RnA; Rb[gA + 1] = RnB; }
      #pragma unroll
      for(int it = 0; it < 8; it++){
        float4 eA = m0exp(va[it], sh[it]);
        float4 eB = m0exp(vb[it], sh[it]);
        tacc[it].x += eA.x*RnA + eB.x*RnB;
        tacc[it].y += eA.y*RnA + eB.y*RnB;
        tacc[it].z += eA.z*RnA + eB.z*RnB;
        tacc[it].w += eA.w*RnA + eB.w*RnB;
      }
    } else {
      float peA=0.f, peB=0.f, sTA=0.f, sTB=0.f, sTPA=0.f, sTPB=0.f;
      #pragma unroll
      for(int it = 0; it < 8; it++){
        float4 eA = m0exp(va[it], sh[it]);
        float4 eB = m0exp(vb[it], sh[it]);
        v4f aA = { eA.x*c4[it].x*RnA, eA.y*c4[it].y*RnA,
                   eA.z*c4[it].z*RnA, eA.w*c4[it].w*RnA };
        v4f aB = { eB.x*c4[it].x*RnB, eB.y*c4[it].y*RnB,
                   eB.z*c4[it].z*RnB, eB.w*c4[it].w*RnB };
        __builtin_nontemporal_store(aA, (v4f*)(out + gA*8192      + it*1024 + t*4));
        __builtin_nontemporal_store(aB, (v4f*)(out + (gA+1)*8192  + it*1024 + t*4));
        peA += (__expf((va[it].x - mA)*TP_INV) + __expf((va[it].y - mA)*TP_INV))
             + (__expf((va[it].z - mA)*TP_INV) + __expf((va[it].w - mA)*TP_INV));
        peB += (__expf((vb[it].x - mB)*TP_INV) + __expf((vb[it].y - mB)*TP_INV))
             + (__expf((vb[it].z - mB)*TP_INV) + __expf((vb[it].w - mB)*TP_INV));
        sTA += (aA[0] + aA[1]) + (aA[2] + aA[3]);
        sTB += (aB[0] + aB[1]) + (aB[2] + aB[3]);
        sTPA += (aA[0]*va[it].x + aA[1]*va[it].y) + (aA[2]*va[it].z + aA[3]*va[it].w);
        sTPB += (aB[0]*vb[it].x + aB[1]*vb[it].y) + (aB[2]*vb[it].z + aB[3]*vb[it].w);
      }
      peA = wredsum(peA); peB = wredsum(peB);
      sTA = wredsum(sTA); sTB = wredsum(sTB);
      sTPA = wredsum(sTPA); sTPB = wredsum(sTPB);
      __syncthreads();
      if((t & 63) == 0){
        sb[wv] = peA; sb[4+wv] = peB; sb[8+wv] = sTA;
        sb[12+wv] = sTB; sb[16+wv] = sTPA; sb[20+wv] = sTPB;
      }
      __syncthreads();
      if(t == 0){
        const float pe0 = (sb[0]+sb[1])+(sb[2]+sb[3]);
        const float pe1 = (sb[4]+sb[5])+(sb[6]+sb[7]);
        const float st0 = (sb[8]+sb[9])+(sb[10]+sb[11]);
        const float st1 = (sb[12]+sb[13])+(sb[14]+sb[15]);
        const float sp0 = (sb[16]+sb[17])+(sb[18]+sb[19]);
        const float sp1 = (sb[20]+sb[21])+(sb[22]+sb[23]);
        const float lse0 = mA * TP_INV + __logf(pe0);
        const float lse1 = mB * TP_INV + __logf(pe1);
        atomicAdd(lossacc, (TP_INV*sp0 - lse0*st0) + (TP_INV*sp1 - lse1*st1));
      }
    }
  }
  if(!LAST){
    float* tp = tbuf + (size_t)b * 8192;
    #pragma unroll
    for(int it = 0; it < 8; it++){
      float* p = tp + it*1024 + t*4;
      atomicAdd(p + 0, tacc[it].x); atomicAdd(p + 1, tacc[it].y);
      atomicAdd(p + 2, tacc[it].z); atomicAdd(p + 3, tacc[it].w);
    }
  }
}

__global__ void finscale_k(const float* __restrict__ lossacc, float* __restrict__ dst){
  dst[0] = -lossacc[0] * (1.0f / 8192.0f);
}

// ---------------------------------------------------------------------------
extern "C" void kernel_launch(void* const* d_in, const int* in_sizes, int n_in,
                              void* d_out, int out_size, void* d_ws, size_t ws_size,
                              hipStream_t stream){
  const float* x = (const float*)d_in[0];   // [32,256,1024]
  const float* W = (const float*)d_in[1];   // [8192,1024]
  float* out = (float*)d_out;               // 32*256*8192 assignments + 1 loss

  char* ws = (char*)d_ws;
  unsigned short* xb   = (unsigned short*)(ws);                 // 16 MB bf16
  unsigned short* Wb   = (unsigned short*)(ws + 16777216);      // 16 MB bf16
  float*    logits     = (float*)   (ws + 33554432);            // 256 MB f32
  unsigned* shiftenc   = (unsigned*)(ws + 301989888);           // 1 MB
  float*    tbuf       = (float*)   (ws + 303038464);           // 1 MB
  float*    Cb         = (float*)   (ws + 304087040);           // 1 MB
  float*    Rb         = (float*)   (ws + 305135616);           // 32 KB
  float*    lossacc    = (float*)   (ws + 305168384);           // 4 B

  init_k   <<<1024, 256, 0, stream>>>(shiftenc, tbuf, Cb, Rb, lossacc);
  norm_x_k <<<8192, 256, 0, stream>>>(x, xb);
  conv_w_k <<<8192, 256, 0, stream>>>(W, Wb);
  gemm_bt_k<<<4096, 256, 0, stream>>>(xb, Wb, logits, shiftenc);
  colsum0_k<<<dim3(32, 32), 256, 0, stream>>>(logits, shiftenc, tbuf);
  // i=1..3: updC (C_i from t_i, zero t), fused iteration (R_i, t_{i+1} / final)
  updC_k  <<<1024, 256, 0, stream>>>(Cb, tbuf);
  iter_k<0><<<dim3(32, 32), 256, 0, stream>>>(logits, shiftenc, Cb, Rb, tbuf,
                                              (float*)nullptr, (float*)nullptr);
  updC_k  <<<1024, 256, 0, stream>>>(Cb, tbuf);
  iter_k<0><<<dim3(32, 32), 256, 0, stream>>>(logits, shiftenc, Cb, Rb, tbuf,
                                              (float*)nullptr, (float*)nullptr);
  updC_k  <<<1024, 256, 0, stream>>>(Cb, tbuf);
  iter_k<1><<<dim3(32, 32), 256, 0, stream>>>(logits, shiftenc, Cb, Rb,
                                              (float*)nullptr, out, lossacc);
  finscale_k<<<1, 1, 0, stream>>>(lossacc, out + (size_t)(out_size - 1));
}

// Round 4
// 903.621 us; speedup vs baseline: 1.5545x; 1.1123x over previous
//
#include <hip/hip_runtime.h>
#include <float.h>

// ---------------------------------------------------------------------------
// OnlineClustering: normalize -> GEMM (bf16 MFMA; epilogue computes per-column
// online-softmax partials) -> merge (shift + C1) -> Sinkhorn (factorized,
// double-buffered fused row+col pass per iteration) -> assignments + loss.
//
// Factorization: M_final[s,k] = M0[s,k]*C[b,k]*R[b,s], M0 = exp((l-shift_k)/T+50).
// GEMM epilogue: per column, over its 128 rows: m_loc = max l, p = sum exp((l-m_loc)/T).
// merge: shift = max m_loc; t1 = e^50 * sum p_i*exp((m_i-shift)/T); C1 = 1/(t1+eps).
// iter<0>: w_s = sum_k M0*C (1 barrier/substep, prefetched); R' = R/(Rw+eps);
//          t' += sum_s M0*R' (e kept in regs, atomics at end).
// iter<1>: same + assignments/loss emitted from registers.
// pbuf (8 MB) lives in d_out, which is dead until iter<1>.
// ---------------------------------------------------------------------------

#define TT_INV 14.285714285714286f   // 1/0.07
#define TP_INV 8.333333333333334f    // 1/0.12
#define EXPMAX 50.0f
#define SK_EPS 1e-8f

typedef short v8s __attribute__((ext_vector_type(8)));
typedef float v4f __attribute__((ext_vector_type(4)));

__device__ inline unsigned short f2bf(float f){          // RNE float->bf16
  unsigned u = __float_as_uint(f);
  u += 0x7FFFu + ((u >> 16) & 1u);
  return (unsigned short)(u >> 16);
}

__device__ inline float wredsum(float v){
  #pragma unroll
  for(int o = 32; o; o >>= 1) v += __shfl_down(v, o);
  return v;
}
__device__ inline float wredmax(float v){
  #pragma unroll
  for(int o = 32; o; o >>= 1) v = fmaxf(v, __shfl_down(v, o));
  return v;
}
__device__ inline float4 m0exp(const float4 v, const float4 sh){
  float4 r;
  r.x = __expf((v.x - sh.x)*TT_INV + EXPMAX);
  r.y = __expf((v.y - sh.y)*TT_INV + EXPMAX);
  r.z = __expf((v.z - sh.z)*TT_INV + EXPMAX);
  r.w = __expf((v.w - sh.w)*TT_INV + EXPMAX);
  return r;
}

// block = 256 threads (4 waves)
__device__ inline float blockReduceSum(float v, float* sb){
  v = wredsum(v);
  __syncthreads();
  if((threadIdx.x & 63) == 0) sb[threadIdx.x >> 6] = v;
  __syncthreads();
  return (sb[0] + sb[1]) + (sb[2] + sb[3]);
}

__device__ inline void gl_lds16(const void* g, void* l){
  __builtin_amdgcn_global_load_lds(
      (const __attribute__((address_space(1))) void*)g,
      (__attribute__((address_space(3))) void*)l, 16, 0, 0);
}

// -------------------- init small buffers --------------------
__global__ __launch_bounds__(256) void init_k(float* __restrict__ tbuf,
                                              float* __restrict__ Rb,
                                              float* __restrict__ lossacc){
  int i = blockIdx.x * 256 + threadIdx.x;   // grid covers 262144
  tbuf[i] = 0.f;
  if(i < 8192) Rb[i] = 1.f;
  if(i == 0) lossacc[0] = 0.f;
}

// -------------------- normalize x rows, cast bf16 --------------------
__global__ __launch_bounds__(256) void norm_x_k(const float* __restrict__ x,
                                                unsigned short* __restrict__ xb){
  const int row = blockIdx.x, t = threadIdx.x;
  const float4 v = ((const float4*)(x + (size_t)row * 1024))[t];
  __shared__ float sb[4];
  float ss = v.x*v.x + v.y*v.y + v.z*v.z + v.w*v.w;
  float tot = blockReduceSum(ss, sb);
  float sc = 1.0f / fmaxf(sqrtf(tot), 1e-7f);
  ushort4 o = { f2bf(v.x*sc), f2bf(v.y*sc), f2bf(v.z*sc), f2bf(v.w*sc) };
  ((ushort4*)(xb + (size_t)row * 1024))[t] = o;
}

// -------------------- cast W bf16 --------------------
__global__ __launch_bounds__(256) void conv_w_k(const float* __restrict__ W,
                                                unsigned short* __restrict__ Wb){
  const size_t i = (size_t)blockIdx.x * 256 + threadIdx.x;
  const float4 v = ((const float4*)W)[i];
  ushort4 o = { f2bf(v.x), f2bf(v.y), f2bf(v.z), f2bf(v.w) };
  ((ushort4*)Wb)[i] = o;
}

// -------------------- bf16 GEMM (B^T form): C[m][n] = sum_d A[m][d]*B[n][d] --
// 128x128 block tile, BK=32, 4 waves each 64x64, global_load_lds width-16.
// Epilogue: per column, (max, sum exp) over this wave's 64 rows -> pbuf[rh].
__global__ __launch_bounds__(256) void gemm_bt_k(const unsigned short* __restrict__ A,
                                                 const unsigned short* __restrict__ B,
                                                 float* __restrict__ C,
                                                 float* __restrict__ pp,
                                                 float* __restrict__ pm){
  __shared__ __align__(16) short As[128 * 32];
  __shared__ __align__(16) short Bs[128 * 32];
  const int t = threadIdx.x;
  const int L = t & 63, w = t >> 6;
  const int wm = w >> 1, wn = w & 1;
  const int quad = L >> 4, lr = L & 15;
  const int m0 = blockIdx.y * 128, n0 = blockIdx.x * 128;

  v4f acc[4][4];
  #pragma unroll
  for(int i = 0; i < 4; i++)
    #pragma unroll
    for(int j = 0; j < 4; j++) acc[i][j] = (v4f){0.f, 0.f, 0.f, 0.f};

  // staging chunks: 512 16B-chunks per tile, 2 per thread per tile
  const int c0 = t, c1 = t + 256;
  const int r0 = c0 >> 2, kc0 = c0 & 3;
  const int r1 = c1 >> 2, kc1 = c1 & 3;
  const unsigned short* gA0 = A + (size_t)(m0 + r0) * 1024 + kc0 * 8;
  const unsigned short* gA1 = A + (size_t)(m0 + r1) * 1024 + kc1 * 8;
  const unsigned short* gB0 = B + (size_t)(n0 + r0) * 1024 + kc0 * 8;
  const unsigned short* gB1 = B + (size_t)(n0 + r1) * 1024 + kc1 * 8;
  short* lA0 = &As[c0 * 8]; short* lA1 = &As[c1 * 8];
  short* lB0 = &Bs[c0 * 8]; short* lB1 = &Bs[c1 * 8];

  for(int kt = 0; kt < 32; ++kt){
    __syncthreads();
    const int ko = kt * 32;
    gl_lds16(gA0 + ko, lA0);
    gl_lds16(gA1 + ko, lA1);
    gl_lds16(gB0 + ko, lB0);
    gl_lds16(gB1 + ko, lB1);
    __syncthreads();
    v8s af[4], bf[4];
    #pragma unroll
    for(int mi = 0; mi < 4; mi++)
      af[mi] = *(const v8s*)&As[(wm*64 + mi*16 + lr) * 32 + quad * 8];
    #pragma unroll
    for(int ni = 0; ni < 4; ni++)
      bf[ni] = *(const v8s*)&Bs[(wn*64 + ni*16 + lr) * 32 + quad * 8];
    #pragma unroll
    for(int mi = 0; mi < 4; mi++)
      #pragma unroll
      for(int ni = 0; ni < 4; ni++)
        acc[mi][ni] = __builtin_amdgcn_mfma_f32_16x16x32_bf16(af[mi], bf[ni], acc[mi][ni], 0, 0, 0);
  }
  // C/D layout: col = lane&15, row = quad*4 + reg. Nontemporal: C is stream-
  // read much later; keep L2 for A/B panels.
  #pragma unroll
  for(int mi = 0; mi < 4; mi++){
    const int row = m0 + wm*64 + mi*16 + quad*4;
    #pragma unroll
    for(int ni = 0; ni < 4; ni++){
      const int col = n0 + wn*64 + ni*16 + lr;
      #pragma unroll
      for(int r = 0; r < 4; r++)
        __builtin_nontemporal_store(acc[mi][ni][r], &C[(size_t)(row + r) * 8192 + col]);
    }
  }
  // fused per-column online-softmax partial over this wave's 64 rows
  const int rh = blockIdx.y * 2 + wm;       // row-half index 0..127
  #pragma unroll
  for(int ni = 0; ni < 4; ni++){
    float m = acc[0][ni][0];
    #pragma unroll
    for(int mi = 0; mi < 4; mi++)
      #pragma unroll
      for(int r = 0; r < 4; r++) m = fmaxf(m, acc[mi][ni][r]);
    m = fmaxf(m, __shfl_xor(m, 16));
    m = fmaxf(m, __shfl_xor(m, 32));
    float p = 0.f;
    #pragma unroll
    for(int mi = 0; mi < 4; mi++)
      #pragma unroll
      for(int r = 0; r < 4; r++) p += __expf((acc[mi][ni][r] - m) * TT_INV);
    p += __shfl_xor(p, 16);
    p += __shfl_xor(p, 32);
    if(quad == 0){
      const int col = n0 + wn*64 + ni*16 + lr;
      pp[(size_t)rh * 8192 + col] = p;
      pm[(size_t)rh * 8192 + col] = m;
    }
  }
}

// -------------------- merge partials -> shift + C1 --------------------
__global__ __launch_bounds__(256) void merge_k(const float* __restrict__ pp,
                                               const float* __restrict__ pm,
                                               float* __restrict__ shf,
                                               float* __restrict__ Cb){
  const int i = blockIdx.x * 256 + threadIdx.x;   // 0..262143 = b*8192 + k
  const int b = i >> 13, k = i & 8191;
  const size_t base = (size_t)(b * 4) * 8192 + k;
  const float m0 = pm[base], m1 = pm[base + 8192], m2 = pm[base + 16384], m3 = pm[base + 24576];
  const float p0 = pp[base], p1 = pp[base + 8192], p2 = pp[base + 16384], p3 = pp[base + 24576];
  const float M = fmaxf(fmaxf(m0, m1), fmaxf(m2, m3));
  float tsum = p0*__expf((m0 - M)*TT_INV) + p1*__expf((m1 - M)*TT_INV)
             + p2*__expf((m2 - M)*TT_INV) + p3*__expf((m3 - M)*TT_INV);
  tsum *= __expf(EXPMAX);
  shf[i] = M;
  Cb[i] = 1.0f / (tsum + SK_EPS);   // C1 (C0 = 1)
}

// -------------------- C update (and reset t for next iter) --------------------
__global__ __launch_bounds__(256) void updC_k(float* __restrict__ Cb,
                                              float* __restrict__ tbuf){
  const int i = blockIdx.x * 256 + threadIdx.x;
  const float c = Cb[i], tt = tbuf[i];
  Cb[i] = c / (c * tt + SK_EPS);
  tbuf[i] = 0.f;
}

// -------------------- fused sinkhorn iteration ------------------------------
// Per block: 8 rows of one batch, 4 substeps of 2 rows, double-buffered
// prefetch, sh/C staged in LDS, substep-unique reduce slots (1 barrier each;
// LAST: 2). !LAST: e kept in regs (no exp recompute); atomics at end.
template<int LAST>
__global__ __launch_bounds__(256, 2) void iter_k(const float* __restrict__ logits,
                                                 const float* __restrict__ shf,
                                                 const float* __restrict__ Cb,
                                                 float* __restrict__ Rb,
                                                 float* __restrict__ tbuf,
                                                 float* __restrict__ out,
                                                 float* __restrict__ lossacc){
  const int sg = blockIdx.x, b = blockIdx.y, t = threadIdx.x;
  __shared__ __align__(16) float shl[8192];
  __shared__ __align__(16) float cl[8192];
  __shared__ float sb[LAST ? 160 : 32];
  const int wv = t >> 6;
  {
    const float* sp = shf + (size_t)b * 8192;
    const float* cp = Cb  + (size_t)b * 8192;
    #pragma unroll
    for(int it = 0; it < 8; it++){
      *(float4*)&shl[it*1024 + t*4] = *(const float4*)(sp + it*1024 + t*4);
      *(float4*)&cl [it*1024 + t*4] = *(const float4*)(cp + it*1024 + t*4);
    }
  }
  __syncthreads();
  const size_t row0 = (size_t)(b*256 + sg*8);
  const float* lbase = logits + row0 * 8192;

  float4 tacc[8];
  if(!LAST){
    #pragma unroll
    for(int it = 0; it < 8; it++) tacc[it] = (float4){0.f,0.f,0.f,0.f};
  }

  float4 A0[8], B0[8], A1[8], B1[8];
  #pragma unroll
  for(int it = 0; it < 8; it++){               // prologue: substep 0 rows
    A0[it] = *(const float4*)(lbase           + it*1024 + t*4);
    B0[it] = *(const float4*)(lbase + 8192    + it*1024 + t*4);
  }

#define SUBSTEP(SUB, VA, VB, NA, NB, PRE)                                      \
{                                                                              \
  const size_t gA = row0 + SUB*2;                                              \
  const float RoA = Rb[gA], RoB = Rb[gA + 1];                                  \
  if(PRE){                                                                     \
    const float* nA = lbase + (size_t)(SUB*2 + 2) * 8192;                      \
    _Pragma("unroll")                                                          \
    for(int it = 0; it < 8; it++){                                             \
      NA[it] = *(const float4*)(nA          + it*1024 + t*4);                  \
      NB[it] = *(const float4*)(nA + 8192   + it*1024 + t*4);                  \
    }                                                                          \
  }                                                                            \
  float wA = 0.f, wB = 0.f, mA = -FLT_MAX, mB = -FLT_MAX;                      \
  _Pragma("unroll")                                                            \
  for(int it = 0; it < 8; it++){                                               \
    const float4 shv = *(const float4*)&shl[it*1024 + t*4];                    \
    const float4 cv  = *(const float4*)&cl [it*1024 + t*4];                    \
    float4 eA = m0exp(VA[it], shv);                                            \
    float4 eB = m0exp(VB[it], shv);                                            \
    wA += (eA.x*cv.x + eA.y*cv.y) + (eA.z*cv.z + eA.w*cv.w);                   \
    wB += (eB.x*cv.x + eB.y*cv.y) + (eB.z*cv.z + eB.w*cv.w);                   \
    if(LAST){                                                                  \
      mA = fmaxf(mA, fmaxf(fmaxf(VA[it].x, VA[it].y), fmaxf(VA[it].z, VA[it].w))); \
      mB = fmaxf(mB, fmaxf(fmaxf(VB[it].x, VB[it].y), fmaxf(VB[it].z, VB[it].w))); \
    } else { VA[it] = eA; VB[it] = eB; }                                       \
  }                                                                            \
  wA = wredsum(wA); wB = wredsum(wB);                                          \
  if(LAST){ mA = wredmax(mA); mB = wredmax(mB); }                              \
  if((t & 63) == 0){                                                           \
    sb[SUB*8 + wv] = wA; sb[SUB*8 + 4 + wv] = wB;                              \
    if(LAST){ sb[32 + SUB*8 + wv] = mA; sb[32 + SUB*8 + 4 + wv] = mB; }        \
  }                                                                            \
  __syncthreads();                                                             \
  wA = (sb[SUB*8+0] + sb[SUB*8+1]) + (sb[SUB*8+2] + sb[SUB*8+3]);              \
  wB = (sb[SUB*8+4] + sb[SUB*8+5]) + (sb[SUB*8+6] + sb[SUB*8+7]);              \
  const float RnA = RoA / (RoA * wA + SK_EPS);                                 \
  const float RnB = RoB / (RoB * wB + SK_EPS);                                 \
  if(!LAST){                                                                   \
    if(t == 0){ Rb[gA] = RnA; Rb[gA + 1] = RnB; }                              \
    _Pragma("unroll")                                                          \
    for(int it = 0; it < 8; it++){                                             \
      tacc[it].x += VA[it].x*RnA + VB[it].x*RnB;                               \
      tacc[it].y += VA[it].y*RnA + VB[it].y*RnB;                               \
      tacc[it].z += VA[it].z*RnA + VB[it].z*RnB;                               \
      tacc[it].w += VA[it].w*RnA + VB[it].w*RnB;                               \
    }                                                                          \
  } else {                                                                     \
    mA = fmaxf(fmaxf(sb[32+SUB*8+0], sb[32+SUB*8+1]),                          \
               fmaxf(sb[32+SUB*8+2], sb[32+SUB*8+3]));                         \
    mB = fmaxf(fmaxf(sb[32+SUB*8+4], sb[32+SUB*8+5]),                          \
               fmaxf(sb[32+SUB*8+6], sb[32+SUB*8+7]));                         \
    float peA=0.f, peB=0.f, sTA=0.f, sTB=0.f, sTPA=0.f, sTPB=0.f;              \
    _Pragma("unroll")                                                          \
    for(int it = 0; it < 8; it++){                                             \
      const float4 shv = *(const float4*)&shl[it*1024 + t*4];                  \
      const float4 cv  = *(const float4*)&cl [it*1024 + t*4];                  \
      float4 eA = m0exp(VA[it], shv);                                          \
      float4 eB = m0exp(VB[it], shv);                                          \
      v4f aA = { eA.x*cv.x*RnA, eA.y*cv.y*RnA, eA.z*cv.z*RnA, eA.w*cv.w*RnA }; \
      v4f aB = { eB.x*cv.x*RnB, eB.y*cv.y*RnB, eB.z*cv.z*RnB, eB.w*cv.w*RnB }; \
      __builtin_nontemporal_store(aA, (v4f*)(out + gA*8192        + it*1024 + t*4)); \
      __builtin_nontemporal_store(aB, (v4f*)(out + (gA+1)*8192    + it*1024 + t*4)); \
      peA += (__expf((VA[it].x - mA)*TP_INV) + __expf((VA[it].y - mA)*TP_INV)) \
           + (__expf((VA[it].z - mA)*TP_INV) + __expf((VA[it].w - mA)*TP_INV)); \
      peB += (__expf((VB[it].x - mB)*TP_INV) + __expf((VB[it].y - mB)*TP_INV)) \
           + (__expf((VB[it].z - mB)*TP_INV) + __expf((VB[it].w - mB)*TP_INV)); \
      sTA += (aA[0] + aA[1]) + (aA[2] + aA[3]);                                \
      sTB += (aB[0] + aB[1]) + (aB[2] + aB[3]);                                \
      sTPA += (aA[0]*VA[it].x + aA[1]*VA[it].y) + (aA[2]*VA[it].z + aA[3]*VA[it].w); \
      sTPB += (aB[0]*VB[it].x + aB[1]*VB[it].y) + (aB[2]*VB[it].z + aB[3]*VB[it].w); \
    }                                                                          \
    peA = wredsum(peA); peB = wredsum(peB);                                    \
    sTA = wredsum(sTA); sTB = wredsum(sTB);                                    \
    sTPA = wredsum(sTPA); sTPB = wredsum(sTPB);                                \
    if((t & 63) == 0){                                                         \
      sb[64 + SUB*24 +      wv] = peA;  sb[64 + SUB*24 +  4 + wv] = peB;       \
      sb[64 + SUB*24 +  8 + wv] = sTA;  sb[64 + SUB*24 + 12 + wv] = sTB;       \
      sb[64 + SUB*24 + 16 + wv] = sTPA; sb[64 + SUB*24 + 20 + wv] = sTPB;      \
    }                                                                          \
    __syncthreads();                                                           \
    if(t == 0){                                                                \
      const float* s4 = &sb[64 + SUB*24];                                      \
      const float pe0 = (s4[0]+s4[1])+(s4[2]+s4[3]);                           \
      const float pe1 = (s4[4]+s4[5])+(s4[6]+s4[7]);                           \
      const float st0 = (s4[8]+s4[9])+(s4[10]+s4[11]);                         \
      const float st1 = (s4[12]+s4[13])+(s4[14]+s4[15]);                       \
      const float sp0 = (s4[16]+s4[17])+(s4[18]+s4[19]);                       \
      const float sp1 = (s4[20]+s4[21])+(s4[22]+s4[23]);                       \
      const float lse0 = mA * TP_INV + __logf(pe0);                            \
      const float lse1 = mB * TP_INV + __logf(pe1);                            \
      atomicAdd(lossacc, (TP_INV*sp0 - lse0*st0) + (TP_INV*sp1 - lse1*st1));   \
    }                                                                          \
  }                                                                            \
}

  SUBSTEP(0, A0, B0, A1, B1, 1)
  SUBSTEP(1, A1, B1, A0, B0, 1)
  SUBSTEP(2, A0, B0, A1, B1, 1)
  SUBSTEP(3, A1, B1, A0, B0, 0)
#undef SUBSTEP

  if(!LAST){
    float* tp = tbuf + (size_t)b * 8192;
    #pragma unroll
    for(int it = 0; it < 8; it++){
      float* p = tp + it*1024 + t*4;
      atomicAdd(p + 0, tacc[it].x); atomicAdd(p + 1, tacc[it].y);
      atomicAdd(p + 2, tacc[it].z); atomicAdd(p + 3, tacc[it].w);
    }
  }
}

__global__ void finscale_k(const float* __restrict__ lossacc, float* __restrict__ dst){
  dst[0] = -lossacc[0] * (1.0f / 8192.0f);
}

// ---------------------------------------------------------------------------
extern "C" void kernel_launch(void* const* d_in, const int* in_sizes, int n_in,
                              void* d_out, int out_size, void* d_ws, size_t ws_size,
                              hipStream_t stream){
  const float* x = (const float*)d_in[0];   // [32,256,1024]
  const float* W = (const float*)d_in[1];   // [8192,1024]
  float* out = (float*)d_out;               // 32*256*8192 assignments + 1 loss

  char* ws = (char*)d_ws;
  unsigned short* xb   = (unsigned short*)(ws);                 // 16 MB bf16
  unsigned short* Wb   = (unsigned short*)(ws + 16777216);      // 16 MB bf16
  float*    logits     = (float*)   (ws + 33554432);            // 256 MB f32
  float*    shf        = (float*)   (ws + 301989888);           // 1 MB
  float*    tbuf       = (float*)   (ws + 303038464);           // 1 MB
  float*    Cb         = (float*)   (ws + 304087040);           // 1 MB
  float*    Rb         = (float*)   (ws + 305135616);           // 32 KB
  float*    lossacc    = (float*)   (ws + 305168384);           // 4 B
  // GEMM-epilogue partials live in d_out (dead until iter<1>): 2 x 4 MB
  float*    pp         = out;                                   // [128][8192]
  float*    pm         = out + 1048576;                         // [128][8192]

  init_k   <<<1024, 256, 0, stream>>>(tbuf, Rb, lossacc);
  norm_x_k <<<8192, 256, 0, stream>>>(x, xb);
  conv_w_k <<<8192, 256, 0, stream>>>(W, Wb);
  gemm_bt_k<<<dim3(64, 64), 256, 0, stream>>>(xb, Wb, logits, pp, pm);
  merge_k  <<<1024, 256, 0, stream>>>(pp, pm, shf, Cb);         // shift + C1
  iter_k<0><<<dim3(32, 32), 256, 0, stream>>>(logits, shf, Cb, Rb, tbuf,
                                              (float*)nullptr, (float*)nullptr);
  updC_k   <<<1024, 256, 0, stream>>>(Cb, tbuf);                // C2
  iter_k<0><<<dim3(32, 32), 256, 0, stream>>>(logits, shf, Cb, Rb, tbuf,
                                              (float*)nullptr, (float*)nullptr);
  updC_k   <<<1024, 256, 0, stream>>>(Cb, tbuf);                // C3
  iter_k<1><<<dim3(32, 32), 256, 0, stream>>>(logits, shf, Cb, Rb,
                                              (float*)nullptr, out, lossacc);
  finscale_k<<<1, 1, 0, stream>>>(lossacc, out + (size_t)(out_size - 1));
}

// Round 5
// 831.322 us; speedup vs baseline: 1.6897x; 1.0870x over previous
//
#include <hip/hip_runtime.h>
#include <float.h>

// ---------------------------------------------------------------------------
// OnlineClustering: normalize -> GEMM (bf16 MFMA; epilogue emits per-column
// online-softmax partials) -> merge (shift + C1) -> Sinkhorn (factorized,
// register-resident fused row+col pass per iteration, atomic-free t-partials)
// -> assignments + loss.
//
// M_final[s,k] = M0[s,k]*C[b,k]*R[b,s], M0 = exp((l-shift_k)/T + 50).
// iter<0>: per row: w = sum_k M0*C ; R' = R/(Rw+eps) ; tacc += M0*R' in regs;
//          block flushes its t-partial slice to tpart (no atomics).
// updC: C' = C/(C*sum_slices + eps).
// iter<1>: same w/R' + assignments (nontemporal) + CE loss.
// pp/pm (8 MB) and tpart (32 MB) live in d_out, dead until iter<1> writes it.
// iter_k: 512 thr, 16 cols/thread -> 80 persistent VGPR, launch_bounds(512,4)
// => 16 waves/CU (2x round-4 occupancy), ~1.3 KB LDS, no spill.
// ---------------------------------------------------------------------------

#define TT_INV 14.285714285714286f   // 1/0.07
#define TP_INV 8.333333333333334f    // 1/0.12
#define EXPMAX 50.0f
#define SK_EPS 1e-8f

typedef short v8s __attribute__((ext_vector_type(8)));
typedef float v4f __attribute__((ext_vector_type(4)));

__device__ inline unsigned short f2bf(float f){          // RNE float->bf16
  unsigned u = __float_as_uint(f);
  u += 0x7FFFu + ((u >> 16) & 1u);
  return (unsigned short)(u >> 16);
}

__device__ inline float wredsum(float v){
  #pragma unroll
  for(int o = 32; o; o >>= 1) v += __shfl_down(v, o);
  return v;
}
__device__ inline float wredmax(float v){
  #pragma unroll
  for(int o = 32; o; o >>= 1) v = fmaxf(v, __shfl_down(v, o));
  return v;
}
__device__ inline float4 m0exp(const float4 v, const float4 sh){
  float4 r;
  r.x = __expf((v.x - sh.x)*TT_INV + EXPMAX);
  r.y = __expf((v.y - sh.y)*TT_INV + EXPMAX);
  r.z = __expf((v.z - sh.z)*TT_INV + EXPMAX);
  r.w = __expf((v.w - sh.w)*TT_INV + EXPMAX);
  return r;
}

// block = 256 threads (4 waves) — used by norm_x only
__device__ inline float blockReduceSum(float v, float* sb){
  v = wredsum(v);
  __syncthreads();
  if((threadIdx.x & 63) == 0) sb[threadIdx.x >> 6] = v;
  __syncthreads();
  return (sb[0] + sb[1]) + (sb[2] + sb[3]);
}

__device__ inline void gl_lds16(const void* g, void* l){
  __builtin_amdgcn_global_load_lds(
      (const __attribute__((address_space(1))) void*)g,
      (__attribute__((address_space(3))) void*)l, 16, 0, 0);
}

// -------------------- init small buffers --------------------
__global__ __launch_bounds__(256) void init_k(float* __restrict__ Rb,
                                              float* __restrict__ lossacc){
  int i = blockIdx.x * 256 + threadIdx.x;   // grid covers 8192
  Rb[i] = 1.f;
  if(i == 0) lossacc[0] = 0.f;
}

// -------------------- normalize x rows, cast bf16 --------------------
__global__ __launch_bounds__(256) void norm_x_k(const float* __restrict__ x,
                                                unsigned short* __restrict__ xb){
  const int row = blockIdx.x, t = threadIdx.x;
  const float4 v = ((const float4*)(x + (size_t)row * 1024))[t];
  __shared__ float sb[4];
  float ss = v.x*v.x + v.y*v.y + v.z*v.z + v.w*v.w;
  float tot = blockReduceSum(ss, sb);
  float sc = 1.0f / fmaxf(sqrtf(tot), 1e-7f);
  ushort4 o = { f2bf(v.x*sc), f2bf(v.y*sc), f2bf(v.z*sc), f2bf(v.w*sc) };
  ((ushort4*)(xb + (size_t)row * 1024))[t] = o;
}

// -------------------- cast W bf16 --------------------
__global__ __launch_bounds__(256) void conv_w_k(const float* __restrict__ W,
                                                unsigned short* __restrict__ Wb){
  const size_t i = (size_t)blockIdx.x * 256 + threadIdx.x;
  const float4 v = ((const float4*)W)[i];
  ushort4 o = { f2bf(v.x), f2bf(v.y), f2bf(v.z), f2bf(v.w) };
  ((ushort4*)Wb)[i] = o;
}

// -------------------- bf16 GEMM (B^T form): C[m][n] = sum_d A[m][d]*B[n][d] --
// 128x128 block tile, BK=32, 4 waves each 64x64, global_load_lds width-16.
// Epilogue: per column, (max, sum exp) over this wave's 64 rows -> pp/pm[rh].
__global__ __launch_bounds__(256) void gemm_bt_k(const unsigned short* __restrict__ A,
                                                 const unsigned short* __restrict__ B,
                                                 float* __restrict__ C,
                                                 float* __restrict__ pp,
                                                 float* __restrict__ pm){
  __shared__ __align__(16) short As[128 * 32];
  __shared__ __align__(16) short Bs[128 * 32];
  const int t = threadIdx.x;
  const int L = t & 63, w = t >> 6;
  const int wm = w >> 1, wn = w & 1;
  const int quad = L >> 4, lr = L & 15;
  const int m0 = blockIdx.y * 128, n0 = blockIdx.x * 128;

  v4f acc[4][4];
  #pragma unroll
  for(int i = 0; i < 4; i++)
    #pragma unroll
    for(int j = 0; j < 4; j++) acc[i][j] = (v4f){0.f, 0.f, 0.f, 0.f};

  // staging chunks: 512 16B-chunks per tile, 2 per thread per tile
  const int c0 = t, c1 = t + 256;
  const int r0 = c0 >> 2, kc0 = c0 & 3;
  const int r1 = c1 >> 2, kc1 = c1 & 3;
  const unsigned short* gA0 = A + (size_t)(m0 + r0) * 1024 + kc0 * 8;
  const unsigned short* gA1 = A + (size_t)(m0 + r1) * 1024 + kc1 * 8;
  const unsigned short* gB0 = B + (size_t)(n0 + r0) * 1024 + kc0 * 8;
  const unsigned short* gB1 = B + (size_t)(n0 + r1) * 1024 + kc1 * 8;
  short* lA0 = &As[c0 * 8]; short* lA1 = &As[c1 * 8];
  short* lB0 = &Bs[c0 * 8]; short* lB1 = &Bs[c1 * 8];

  for(int kt = 0; kt < 32; ++kt){
    __syncthreads();
    const int ko = kt * 32;
    gl_lds16(gA0 + ko, lA0);
    gl_lds16(gA1 + ko, lA1);
    gl_lds16(gB0 + ko, lB0);
    gl_lds16(gB1 + ko, lB1);
    __syncthreads();
    v8s af[4], bf[4];
    #pragma unroll
    for(int mi = 0; mi < 4; mi++)
      af[mi] = *(const v8s*)&As[(wm*64 + mi*16 + lr) * 32 + quad * 8];
    #pragma unroll
    for(int ni = 0; ni < 4; ni++)
      bf[ni] = *(const v8s*)&Bs[(wn*64 + ni*16 + lr) * 32 + quad * 8];
    #pragma unroll
    for(int mi = 0; mi < 4; mi++)
      #pragma unroll
      for(int ni = 0; ni < 4; ni++)
        acc[mi][ni] = __builtin_amdgcn_mfma_f32_16x16x32_bf16(af[mi], bf[ni], acc[mi][ni], 0, 0, 0);
  }
  // C/D layout: col = lane&15, row = quad*4 + reg
  #pragma unroll
  for(int mi = 0; mi < 4; mi++){
    const int row = m0 + wm*64 + mi*16 + quad*4;
    #pragma unroll
    for(int ni = 0; ni < 4; ni++){
      const int col = n0 + wn*64 + ni*16 + lr;
      #pragma unroll
      for(int r = 0; r < 4; r++)
        C[(size_t)(row + r) * 8192 + col] = acc[mi][ni][r];
    }
  }
  // fused per-column online-softmax partial over this wave's 64 rows
  const int rh = blockIdx.y * 2 + wm;       // row-half index 0..127
  #pragma unroll
  for(int ni = 0; ni < 4; ni++){
    float m = acc[0][ni][0];
    #pragma unroll
    for(int mi = 0; mi < 4; mi++)
      #pragma unroll
      for(int r = 0; r < 4; r++) m = fmaxf(m, acc[mi][ni][r]);
    m = fmaxf(m, __shfl_xor(m, 16));
    m = fmaxf(m, __shfl_xor(m, 32));
    float p = 0.f;
    #pragma unroll
    for(int mi = 0; mi < 4; mi++)
      #pragma unroll
      for(int r = 0; r < 4; r++) p += __expf((acc[mi][ni][r] - m) * TT_INV);
    p += __shfl_xor(p, 16);
    p += __shfl_xor(p, 32);
    if(quad == 0){
      const int col = n0 + wn*64 + ni*16 + lr;
      pp[(size_t)rh * 8192 + col] = p;
      pm[(size_t)rh * 8192 + col] = m;
    }
  }
}

// -------------------- merge partials -> shift + C1 --------------------
__global__ __launch_bounds__(256) void merge_k(const float* __restrict__ pp,
                                               const float* __restrict__ pm,
                                               float* __restrict__ shf,
                                               float* __restrict__ Cb){
  const int i = blockIdx.x * 256 + threadIdx.x;   // 0..262143 = b*8192 + k
  const int b = i >> 13, k = i & 8191;
  const size_t base = (size_t)(b * 4) * 8192 + k;
  const float m0 = pm[base], m1 = pm[base + 8192], m2 = pm[base + 16384], m3 = pm[base + 24576];
  const float p0 = pp[base], p1 = pp[base + 8192], p2 = pp[base + 16384], p3 = pp[base + 24576];
  const float M = fmaxf(fmaxf(m0, m1), fmaxf(m2, m3));
  float tsum = p0*__expf((m0 - M)*TT_INV) + p1*__expf((m1 - M)*TT_INV)
             + p2*__expf((m2 - M)*TT_INV) + p3*__expf((m3 - M)*TT_INV);
  tsum *= __expf(EXPMAX);
  shf[i] = M;
  Cb[i] = 1.0f / (tsum + SK_EPS);   // C1 (C0 = 1)
}

// -------------------- C update from t-partial slices --------------------
__global__ __launch_bounds__(256) void updC_k(float* __restrict__ Cb,
                                              const float* __restrict__ tpart){
  const int i = blockIdx.x * 256 + threadIdx.x;   // 262144 = b*8192 + k
  const int b = i >> 13, k = i & 8191;
  const float* p = tpart + (size_t)(b * 32) * 8192 + k;
  float s = 0.f;
  #pragma unroll
  for(int j = 0; j < 32; j++) s += p[(size_t)j * 8192];
  const float c = Cb[i];
  Cb[i] = c / (c * s + SK_EPS);
}

// -------------------- fused sinkhorn iteration ------------------------------
// 512 threads, 16 cols/thread (cols = it*2048 + t*4, it=0..3), 8 rows/block,
// 1-row substeps double-buffered. w-reduce in substep-unique LDS slots
// (1 barrier; LAST: 2). t-partials -> tpart slice (no atomics).
template<int LAST>
__global__ __launch_bounds__(512, 4) void iter_k(const float* __restrict__ logits,
                                                 const float* __restrict__ shf,
                                                 const float* __restrict__ Cb,
                                                 float* __restrict__ Rb,
                                                 float* __restrict__ tpart,
                                                 float* __restrict__ out,
                                                 float* __restrict__ lossacc){
  const int sg = blockIdx.x, b = blockIdx.y, t = threadIdx.x;
  __shared__ float sb[LAST ? 320 : 64];
  const int wv = t >> 6;                    // wave 0..7
  float4 sh4[4], cc4[4];
  #pragma unroll
  for(int it = 0; it < 4; it++){
    sh4[it] = *(const float4*)(shf + (size_t)b*8192 + it*2048 + t*4);
    cc4[it] = *(const float4*)(Cb  + (size_t)b*8192 + it*2048 + t*4);
  }
  float4 tacc[4];
  if(!LAST){
    #pragma unroll
    for(int it = 0; it < 4; it++) tacc[it] = (float4){0.f,0.f,0.f,0.f};
  }
  const size_t row0 = (size_t)(b*256 + sg*8);
  const float* lbase = logits + row0 * 8192;

  float4 V[4], N[4];
  #pragma unroll
  for(int it = 0; it < 4; it++)             // prologue: row 0
    V[it] = *(const float4*)(lbase + it*2048 + t*4);

#define SUBSTEP(R, VV, NN, PRE)                                                \
{                                                                              \
  const size_t g = row0 + R;                                                   \
  const float Ro = Rb[g];                                                      \
  if(PRE){                                                                     \
    const float* np = lbase + (size_t)(R + 1) * 8192;                          \
    _Pragma("unroll")                                                          \
    for(int it = 0; it < 4; it++)                                              \
      NN[it] = *(const float4*)(np + it*2048 + t*4);                           \
  }                                                                            \
  float w = 0.f, mR = -FLT_MAX;                                                \
  _Pragma("unroll")                                                            \
  for(int it = 0; it < 4; it++){                                               \
    float4 e = m0exp(VV[it], sh4[it]);                                         \
    w += (e.x*cc4[it].x + e.y*cc4[it].y) + (e.z*cc4[it].z + e.w*cc4[it].w);    \
    if(LAST){                                                                  \
      mR = fmaxf(mR, fmaxf(fmaxf(VV[it].x, VV[it].y), fmaxf(VV[it].z, VV[it].w))); \
    } else { VV[it] = e; }                                                     \
  }                                                                            \
  w = wredsum(w);                                                              \
  if(LAST) mR = wredmax(mR);                                                   \
  if((t & 63) == 0){                                                           \
    sb[R*(LAST ? 16 : 8) + wv] = w;                                            \
    if(LAST) sb[R*16 + 8 + wv] = mR;                                           \
  }                                                                            \
  __syncthreads();                                                             \
  {                                                                            \
    const float* s8 = &sb[R*(LAST ? 16 : 8)];                                  \
    w = ((s8[0]+s8[1]) + (s8[2]+s8[3])) + ((s8[4]+s8[5]) + (s8[6]+s8[7]));     \
  }                                                                            \
  const float Rn = Ro / (Ro * w + SK_EPS);                                     \
  if(!LAST){                                                                   \
    if(t == 0) Rb[g] = Rn;                                                     \
    _Pragma("unroll")                                                          \
    for(int it = 0; it < 4; it++){                                             \
      tacc[it].x += VV[it].x * Rn; tacc[it].y += VV[it].y * Rn;                \
      tacc[it].z += VV[it].z * Rn; tacc[it].w += VV[it].w * Rn;                \
    }                                                                          \
  } else {                                                                     \
    {                                                                          \
      const float* m8 = &sb[R*16 + 8];                                         \
      mR = fmaxf(fmaxf(fmaxf(m8[0],m8[1]), fmaxf(m8[2],m8[3])),                \
                 fmaxf(fmaxf(m8[4],m8[5]), fmaxf(m8[6],m8[7])));               \
    }                                                                          \
    float pe = 0.f, sT = 0.f, sTP = 0.f;                                       \
    _Pragma("unroll")                                                          \
    for(int it = 0; it < 4; it++){                                             \
      float4 e = m0exp(VV[it], sh4[it]);                                       \
      v4f a = { e.x*cc4[it].x*Rn, e.y*cc4[it].y*Rn,                            \
                e.z*cc4[it].z*Rn, e.w*cc4[it].w*Rn };                          \
      __builtin_nontemporal_store(a, (v4f*)(out + g*8192 + it*2048 + t*4));    \
      pe += (__expf((VV[it].x - mR)*TP_INV) + __expf((VV[it].y - mR)*TP_INV))  \
          + (__expf((VV[it].z - mR)*TP_INV) + __expf((VV[it].w - mR)*TP_INV)); \
      sT += (a[0] + a[1]) + (a[2] + a[3]);                                     \
      sTP += (a[0]*VV[it].x + a[1]*VV[it].y) + (a[2]*VV[it].z + a[3]*VV[it].w);\
    }                                                                          \
    pe = wredsum(pe); sT = wredsum(sT); sTP = wredsum(sTP);                    \
    if((t & 63) == 0){                                                         \
      sb[128 + R*24 +      wv] = pe;                                           \
      sb[128 + R*24 +  8 + wv] = sT;                                           \
      sb[128 + R*24 + 16 + wv] = sTP;                                          \
    }                                                                          \
    __syncthreads();                                                           \
    if(t == 0){                                                                \
      const float* s8 = &sb[128 + R*24];                                       \
      const float pe8 = ((s8[0]+s8[1])+(s8[2]+s8[3]))+((s8[4]+s8[5])+(s8[6]+s8[7])); \
      const float st8 = ((s8[8]+s8[9])+(s8[10]+s8[11]))+((s8[12]+s8[13])+(s8[14]+s8[15])); \
      const float sp8 = ((s8[16]+s8[17])+(s8[18]+s8[19]))+((s8[20]+s8[21])+(s8[22]+s8[23])); \
      const float lse = mR * TP_INV + __logf(pe8);                             \
      atomicAdd(lossacc, TP_INV * sp8 - lse * st8);                            \
    }                                                                          \
  }                                                                            \
}

  SUBSTEP(0, V, N, 1)
  SUBSTEP(1, N, V, 1)
  SUBSTEP(2, V, N, 1)
  SUBSTEP(3, N, V, 1)
  SUBSTEP(4, V, N, 1)
  SUBSTEP(5, N, V, 1)
  SUBSTEP(6, V, N, 1)
  SUBSTEP(7, N, V, 0)
#undef SUBSTEP

  if(!LAST){
    float* tp = tpart + (size_t)(b * 32 + sg) * 8192;
    #pragma unroll
    for(int it = 0; it < 4; it++)
      *(float4*)(tp + it*2048 + t*4) = tacc[it];
  }
}

__global__ void finscale_k(const float* __restrict__ lossacc, float* __restrict__ dst){
  dst[0] = -lossacc[0] * (1.0f / 8192.0f);
}

// ---------------------------------------------------------------------------
extern "C" void kernel_launch(void* const* d_in, const int* in_sizes, int n_in,
                              void* d_out, int out_size, void* d_ws, size_t ws_size,
                              hipStream_t stream){
  const float* x = (const float*)d_in[0];   // [32,256,1024]
  const float* W = (const float*)d_in[1];   // [8192,1024]
  float* out = (float*)d_out;               // 32*256*8192 assignments + 1 loss

  char* ws = (char*)d_ws;
  unsigned short* xb   = (unsigned short*)(ws);                 // 16 MB bf16
  unsigned short* Wb   = (unsigned short*)(ws + 16777216);      // 16 MB bf16
  float*    logits     = (float*)   (ws + 33554432);            // 256 MB f32
  float*    shf        = (float*)   (ws + 301989888);           // 1 MB
  float*    Cb         = (float*)   (ws + 303038464);           // 1 MB
  float*    Rb         = (float*)   (ws + 304087040);           // 32 KB
  float*    lossacc    = (float*)   (ws + 304119808);           // 4 B
  // scratch hosted in d_out (dead until iter<1> writes it):
  float*    pp         = out;                                   // 4 MB [128][8192]
  float*    pm         = out + 1048576;                         // 4 MB [128][8192]
  float*    tpart      = out;                                   // 32 MB [1024][8192]

  init_k   <<<32, 256, 0, stream>>>(Rb, lossacc);
  norm_x_k <<<8192, 256, 0, stream>>>(x, xb);
  conv_w_k <<<8192, 256, 0, stream>>>(W, Wb);
  gemm_bt_k<<<dim3(64, 64), 256, 0, stream>>>(xb, Wb, logits, pp, pm);
  merge_k  <<<1024, 256, 0, stream>>>(pp, pm, shf, Cb);         // shift + C1
  iter_k<0><<<dim3(32, 32), 512, 0, stream>>>(logits, shf, Cb, Rb, tpart,
                                              (float*)nullptr, (float*)nullptr);
  updC_k   <<<1024, 256, 0, stream>>>(Cb, tpart);               // C2
  iter_k<0><<<dim3(32, 32), 512, 0, stream>>>(logits, shf, Cb, Rb, tpart,
                                              (float*)nullptr, (float*)nullptr);
  updC_k   <<<1024, 256, 0, stream>>>(Cb, tpart);               // C3
  iter_k<1><<<dim3(32, 32), 512, 0, stream>>>(logits, shf, Cb, Rb,
                                              (float*)nullptr, out, lossacc);
  finscale_k<<<1, 1, 0, stream>>>(lossacc, out + (size_t)(out_size - 1));
}